// Round 2
// baseline (265.244 us; speedup 1.0000x reference)
//
#include <hip/hip_runtime.h>
#include <hip/hip_bf16.h>

#define BATCH 16
#define CH    256
#define HW    1024
#define NH    4
#define DH    64
#define NG    32
#define CPG   8
#define EPSV  1e-6f

// log2(e) / sqrt(C) folded into Q so softmax = exp2(S_scaled)
#define QSCALE 0.090168440055558706f

typedef __bf16 bf16x8 __attribute__((ext_vector_type(8)));
typedef float  f32x4  __attribute__((ext_vector_type(4)));

__device__ __forceinline__ unsigned short f2bf(float f) {
    union { __hip_bfloat16 h; unsigned short u; } cv;
    cv.h = __float2bfloat16(f);
    return cv.u;
}

// ---------------- prep: weight transpose fp32[c][d] -> bf16[n][c], bias concat ----
__global__ void prep_kernel(const float* Wq, const float* Wk, const float* Wv,
                            const float* Wp, const float* bq, const float* bk,
                            const float* bv, unsigned short* wqkv_t,
                            unsigned short* wp_t, float* bqkv) {
    int idx = blockIdx.x * 256 + threadIdx.x;
    if (idx < 768 * 256) {
        int n = idx >> 8, c = idx & 255;
        const float* W = (n < 256) ? Wq : (n < 512) ? Wk : Wv;
        int d = n & 255;
        wqkv_t[idx] = f2bf(W[c * 256 + d]);
    } else if (idx < 768 * 256 + 256 * 256) {
        int j = idx - 768 * 256;
        int n = j >> 8, c = j & 255;
        wp_t[j] = f2bf(Wp[c * 256 + n]);
    }
    if (idx < 768)
        bqkv[idx] = (idx < 256) ? bq[idx] : (idx < 512) ? bk[idx - 256] : bv[idx - 512];
}

// ---------------- GroupNorm pass 1: per (b,g) mean/rstd --------------------------
__global__ void gn_stats_kernel(const float* x, float* gmean, float* grstd) {
    int bg = blockIdx.x;                       // 0..511, group data is contiguous
    const float* p = x + (size_t)bg * (CPG * HW);
    int t = threadIdx.x;
    float s = 0.f, ss = 0.f;
    for (int i = t; i < CPG * HW; i += 256) {
        float v = p[i];
        s += v; ss += v * v;
    }
    for (int o = 32; o; o >>= 1) { s += __shfl_down(s, o); ss += __shfl_down(ss, o); }
    __shared__ float as[4], ass[4];
    int w = t >> 6;
    if ((t & 63) == 0) { as[w] = s; ass[w] = ss; }
    __syncthreads();
    if (t == 0) {
        float S = as[0] + as[1] + as[2] + as[3];
        float SS = ass[0] + ass[1] + ass[2] + ass[3];
        float mean = S / (float)(CPG * HW);
        float var = SS / (float)(CPG * HW) - mean * mean;
        gmean[bg] = mean;
        grstd[bg] = rsqrtf(var + EPSV);
    }
}

// ---------------- GroupNorm pass 2: normalize + transpose to xn_t[b][p][c] bf16 --
__global__ void gn_apply_kernel(const float* x, const float* scale, const float* bias,
                                const float* gmean, const float* grstd,
                                unsigned short* xn_t) {
    int b = blockIdx.y;
    int p0 = blockIdx.x * 64;
    int t = threadIdx.x;
    __shared__ unsigned short lds[64][CH + 8];     // row stride 264*2B = 16B-aligned
    int pp = t & 63, cq = t >> 6;
    const float* xb = x + (size_t)b * CH * HW;
    for (int c0 = 0; c0 < CH; c0 += 4) {
        int c = c0 + cq;
        int g = b * NG + (c >> 3);
        float m = gmean[g], r = grstd[g];
        float v = xb[(size_t)c * HW + p0 + pp];
        lds[pp][c] = f2bf((v - m) * r * scale[c] + bias[c]);
    }
    __syncthreads();
    unsigned short* dst = xn_t + ((size_t)b * HW + p0) * CH;
    for (int pass = 0; pass < 4; pass++) {
        int row = pass * 16 + (t >> 4);
        int c = (t & 15) * 16;
        ulonglong2 v0 = *reinterpret_cast<ulonglong2*>(&lds[row][c]);
        ulonglong2 v1 = *reinterpret_cast<ulonglong2*>(&lds[row][c + 8]);
        *reinterpret_cast<ulonglong2*>(dst + (size_t)row * CH + c) = v0;
        *reinterpret_cast<ulonglong2*>(dst + (size_t)row * CH + c + 8) = v1;
    }
}

// ---------------- QKV GEMM: (16384 x 256) x (256 x 768), bf16 MFMA ---------------
// A = xn_t[m][k] row-major; B = wqkv_t[n][k] row-major. 128x128/block, 64x64/wave.
// Q is pre-scaled by QSCALE so attention softmax needs only exp2.
__global__ __launch_bounds__(256) void qkv_kernel(const unsigned short* xn_t,
        const unsigned short* wqkv_t, const float* bqkv,
        unsigned short* qb, unsigned short* kb, unsigned short* vb) {
    int t = threadIdx.x;
    int wv = t >> 6, lane = t & 63, quad = lane >> 4, ln = lane & 15;
    int wr = wv >> 1, wc = wv & 1;
    int m0 = blockIdx.x * 128 + wr * 64;
    int n0 = blockIdx.y * 128 + wc * 64;

    f32x4 acc[4][4] = {};
    for (int k0 = 0; k0 < CH; k0 += 32) {
        int koff = k0 + quad * 8;
        bf16x8 af[4], bfr[4];
#pragma unroll
        for (int i = 0; i < 4; i++)
            af[i] = *reinterpret_cast<const bf16x8*>(xn_t + (size_t)(m0 + i * 16 + ln) * CH + koff);
#pragma unroll
        for (int j = 0; j < 4; j++)
            bfr[j] = *reinterpret_cast<const bf16x8*>(wqkv_t + (size_t)(n0 + j * 16 + ln) * CH + koff);
#pragma unroll
        for (int i = 0; i < 4; i++)
#pragma unroll
            for (int j = 0; j < 4; j++)
                acc[i][j] = __builtin_amdgcn_mfma_f32_16x16x32_bf16(af[i], bfr[j], acc[i][j], 0, 0, 0);
    }
#pragma unroll
    for (int j = 0; j < 4; j++) {
        int n = n0 + j * 16 + ln;
        float bias = bqkv[n];
        int which = n >> 8;              // uniform per 16-tile
        int dh_ = n & 255;
        int head = dh_ >> 6, d = dh_ & 63;
#pragma unroll
        for (int i = 0; i < 4; i++) {
            int mb = m0 + i * 16 + quad * 4;
            int bi = mb >> 10, p = mb & 1023;
            int bh = bi * NH + head;
            if (which < 2) {
                unsigned short* dst = (which == 0 ? qb : kb) + (size_t)bh * HW * DH;
                float sc = (which == 0) ? QSCALE : 1.0f;
#pragma unroll
                for (int r = 0; r < 4; r++)
                    dst[(size_t)(p + r) * DH + d] = f2bf((acc[i][j][r] + bias) * sc);
            } else {
                unsigned short* dst = vb + ((size_t)bh * DH + d) * HW + p;
                ushort4 pk4;
                pk4.x = f2bf(acc[i][j][0] + bias);
                pk4.y = f2bf(acc[i][j][1] + bias);
                pk4.z = f2bf(acc[i][j][2] + bias);
                pk4.w = f2bf(acc[i][j][3] + bias);
                *reinterpret_cast<ushort4*>(dst) = pk4;
            }
        }
    }
}

// ---------------- attention, no-max softmax (scores are O(1) by construction) -----
// Per wave: 16 queries. S^T = K·Q^T (Q pre-scaled by log2e/16) -> exp2 ->
// per-lane partial expsum (reduced ONCE at end) -> P^T via per-wave LDS ->
// O^T = V^T·P^T. No per-iteration cross-lane ops, no O rescale.
__global__ __launch_bounds__(256) void attn_kernel(const unsigned short* qb,
        const unsigned short* kb, const unsigned short* vb, unsigned short* h_t) {
    int qblk = blockIdx.x, bh = blockIdx.y;
    int t = threadIdx.x;
    int wv = t >> 6, lane = t & 63, quad = lane >> 4, ln = lane & 15;
    int q0 = qblk * 64 + wv * 16;

    const unsigned short* Q = qb + (size_t)bh * HW * DH;
    const unsigned short* K = kb + (size_t)bh * HW * DH;
    const unsigned short* V = vb + (size_t)bh * DH * HW;

    __shared__ unsigned short pbuf[4][16][72];   // per-wave P^T[pq][pk]

    bf16x8 qf[2];
#pragma unroll
    for (int kk = 0; kk < 2; kk++)
        qf[kk] = *reinterpret_cast<const bf16x8*>(Q + (size_t)(q0 + ln) * DH + kk * 32 + quad * 8);

    f32x4 ls = {0.f, 0.f, 0.f, 0.f};
    f32x4 o[4] = {};

    for (int k0 = 0; k0 < HW; k0 += 64) {
        // issue ALL global loads for this iteration up front (latency hiding)
        bf16x8 kf[4][2], vf[4][2];
#pragma unroll
        for (int mt = 0; mt < 4; mt++) {
            const unsigned short* kp = K + (size_t)(k0 + mt * 16 + ln) * DH + quad * 8;
            kf[mt][0] = *reinterpret_cast<const bf16x8*>(kp);
            kf[mt][1] = *reinterpret_cast<const bf16x8*>(kp + 32);
        }
#pragma unroll
        for (int mt = 0; mt < 4; mt++) {
            const unsigned short* vp = V + (size_t)(mt * 16 + ln) * HW + k0 + quad * 8;
            vf[mt][0] = *reinterpret_cast<const bf16x8*>(vp);
            vf[mt][1] = *reinterpret_cast<const bf16x8*>(vp + 32);
        }

        f32x4 s[4] = {};
#pragma unroll
        for (int mt = 0; mt < 4; mt++) {
            s[mt] = __builtin_amdgcn_mfma_f32_16x16x32_bf16(kf[mt][0], qf[0], s[mt], 0, 0, 0);
            s[mt] = __builtin_amdgcn_mfma_f32_16x16x32_bf16(kf[mt][1], qf[1], s[mt], 0, 0, 0);
        }
        // exp2 (scale pre-folded into Q), accumulate per-lane expsum, pack to LDS
#pragma unroll
        for (int mt = 0; mt < 4; mt++) {
            ushort4 pk4;
            float e0 = exp2f(s[mt][0]); ls[0] += e0; pk4.x = f2bf(e0);
            float e1 = exp2f(s[mt][1]); ls[1] += e1; pk4.y = f2bf(e1);
            float e2 = exp2f(s[mt][2]); ls[2] += e2; pk4.z = f2bf(e2);
            float e3 = exp2f(s[mt][3]); ls[3] += e3; pk4.w = f2bf(e3);
            *reinterpret_cast<ushort4*>(&pbuf[wv][ln][mt * 16 + quad * 4]) = pk4;
        }
#pragma unroll
        for (int kk = 0; kk < 2; kk++) {
            bf16x8 pf = *reinterpret_cast<const bf16x8*>(&pbuf[wv][ln][kk * 32 + quad * 8]);
#pragma unroll
            for (int mt = 0; mt < 4; mt++)
                o[mt] = __builtin_amdgcn_mfma_f32_16x16x32_bf16(vf[mt][kk], pf, o[mt], 0, 0, 0);
        }
    }
    // single cross-lane reduction of the expsum (per query column ln)
    float lsum = ls[0] + ls[1] + ls[2] + ls[3];
    lsum += __shfl_xor(lsum, 16);
    lsum += __shfl_xor(lsum, 32);
    float inv = 1.0f / lsum;

    int b = bh >> 2, head = bh & 3;
    unsigned short* dst = h_t + ((size_t)b * HW + q0 + ln) * CH + head * DH;
#pragma unroll
    for (int mt = 0; mt < 4; mt++) {
        ushort4 pk4;
        pk4.x = f2bf(o[mt][0] * inv);
        pk4.y = f2bf(o[mt][1] * inv);
        pk4.z = f2bf(o[mt][2] * inv);
        pk4.w = f2bf(o[mt][3] * inv);
        *reinterpret_cast<ushort4*>(dst + mt * 16 + quad * 4) = pk4;
    }
}

// ---------------- proj GEMM + bias + residual + /sqrt(2) -------------------------
__global__ __launch_bounds__(256) void proj_kernel(const unsigned short* h_t,
        const unsigned short* wp_t, const float* bp, const float* x, float* out) {
    int t = threadIdx.x;
    int wv = t >> 6, lane = t & 63, quad = lane >> 4, ln = lane & 15;
    int wr = wv >> 1, wc = wv & 1;
    int m0 = blockIdx.x * 128 + wr * 64;
    int n0 = blockIdx.y * 128 + wc * 64;

    f32x4 acc[4][4] = {};
    for (int k0 = 0; k0 < CH; k0 += 32) {
        int koff = k0 + quad * 8;
        bf16x8 af[4], bfr[4];
#pragma unroll
        for (int i = 0; i < 4; i++)
            af[i] = *reinterpret_cast<const bf16x8*>(h_t + (size_t)(m0 + i * 16 + ln) * CH + koff);
#pragma unroll
        for (int j = 0; j < 4; j++)
            bfr[j] = *reinterpret_cast<const bf16x8*>(wp_t + (size_t)(n0 + j * 16 + ln) * CH + koff);
#pragma unroll
        for (int i = 0; i < 4; i++)
#pragma unroll
            for (int j = 0; j < 4; j++)
                acc[i][j] = __builtin_amdgcn_mfma_f32_16x16x32_bf16(af[i], bfr[j], acc[i][j], 0, 0, 0);
    }
    const float inv_s2 = 0.70710678118654752440f;
#pragma unroll
    for (int j = 0; j < 4; j++) {
        int n = n0 + j * 16 + ln;
        float bias = bp[n];
#pragma unroll
        for (int i = 0; i < 4; i++) {
            int mb = m0 + i * 16 + quad * 4;
            int bi = mb >> 10, p = mb & 1023;
            size_t off = ((size_t)(bi * CH + n)) * HW + p;
            float4 xv = *reinterpret_cast<const float4*>(x + off);
            float4 ov;
            ov.x = (xv.x + acc[i][j][0] + bias) * inv_s2;
            ov.y = (xv.y + acc[i][j][1] + bias) * inv_s2;
            ov.z = (xv.z + acc[i][j][2] + bias) * inv_s2;
            ov.w = (xv.w + acc[i][j][3] + bias) * inv_s2;
            *reinterpret_cast<float4*>(out + off) = ov;
        }
    }
}

extern "C" void kernel_launch(void* const* d_in, const int* in_sizes, int n_in,
                              void* d_out, int out_size, void* d_ws, size_t ws_size,
                              hipStream_t stream) {
    const float* x        = (const float*)d_in[0];
    const float* gn_scale = (const float*)d_in[1];
    const float* gn_bias  = (const float*)d_in[2];
    const float* Wq = (const float*)d_in[3];
    const float* bq = (const float*)d_in[4];
    const float* Wk = (const float*)d_in[5];
    const float* bk = (const float*)d_in[6];
    const float* Wv = (const float*)d_in[7];
    const float* bv = (const float*)d_in[8];
    const float* Wp = (const float*)d_in[9];
    const float* bp = (const float*)d_in[10];
    float* out = (float*)d_out;

    char* ws = (char*)d_ws;
    // ws layout (bytes); h_t aliases xn_t (xn_t dead after qkv_kernel). Total ~32.5 MB.
    float*          gmean  = (float*)(ws + 0);
    float*          grstd  = (float*)(ws + 2048);
    float*          bqkv   = (float*)(ws + 4096);
    unsigned short* wqkv_t = (unsigned short*)(ws + 8192);
    unsigned short* wp_t   = (unsigned short*)(ws + 401408);
    unsigned short* xn_t   = (unsigned short*)(ws + 532480);
    unsigned short* h_t    = xn_t;
    unsigned short* qb     = (unsigned short*)(ws + 8921088);
    unsigned short* kb     = (unsigned short*)(ws + 17309696);
    unsigned short* vb     = (unsigned short*)(ws + 25698304);

    prep_kernel<<<1024, 256, 0, stream>>>(Wq, Wk, Wv, Wp, bq, bk, bv, wqkv_t, wp_t, bqkv);
    gn_stats_kernel<<<512, 256, 0, stream>>>(x, gmean, grstd);
    gn_apply_kernel<<<dim3(16, 16), 256, 0, stream>>>(x, gn_scale, gn_bias, gmean, grstd, xn_t);
    qkv_kernel<<<dim3(128, 6), 256, 0, stream>>>(xn_t, wqkv_t, bqkv, qb, kb, vb);
    attn_kernel<<<dim3(16, 64), 256, 0, stream>>>(qb, kb, vb, h_t);
    proj_kernel<<<dim3(128, 2), 256, 0, stream>>>(h_t, wp_t, bp, x, out);
}

// Round 3
// 189.309 us; speedup vs baseline: 1.4011x; 1.4011x over previous
//
#include <hip/hip_runtime.h>
#include <hip/hip_bf16.h>

#define BATCH 16
#define CH    256
#define HW    1024
#define NH    4
#define DH    64
#define NG    32
#define CPG   8
#define EPSV  1e-6f

// log2(e) / sqrt(C) folded into Q so softmax = exp2(S_scaled)
#define QSCALE 0.090168440055558706f

typedef __bf16 bf16x8 __attribute__((ext_vector_type(8)));
typedef float  f32x4  __attribute__((ext_vector_type(4)));

__device__ __forceinline__ unsigned short f2bf(float f) {
    union { __hip_bfloat16 h; unsigned short u; } cv;
    cv.h = __float2bfloat16(f);
    return cv.u;
}

__device__ __forceinline__ void gld_lds16(const unsigned short* g, unsigned short* l) {
    __builtin_amdgcn_global_load_lds(
        (const __attribute__((address_space(1))) void*)g,
        (__attribute__((address_space(3))) void*)l, 16, 0, 0);
}

// ---------------- prep: weight transpose fp32[c][d] -> bf16[n][c], bias concat ----
__global__ void prep_kernel(const float* Wq, const float* Wk, const float* Wv,
                            const float* Wp, const float* bq, const float* bk,
                            const float* bv, unsigned short* wqkv_t,
                            unsigned short* wp_t, float* bqkv) {
    int idx = blockIdx.x * 256 + threadIdx.x;
    if (idx < 768 * 256) {
        int n = idx >> 8, c = idx & 255;
        const float* W = (n < 256) ? Wq : (n < 512) ? Wk : Wv;
        int d = n & 255;
        wqkv_t[idx] = f2bf(W[c * 256 + d]);
    } else if (idx < 768 * 256 + 256 * 256) {
        int j = idx - 768 * 256;
        int n = j >> 8, c = j & 255;
        wp_t[j] = f2bf(Wp[c * 256 + n]);
    }
    if (idx < 768)
        bqkv[idx] = (idx < 256) ? bq[idx] : (idx < 512) ? bk[idx - 256] : bv[idx - 512];
}

// ---------------- GroupNorm pass 1: per (b,g) mean/rstd --------------------------
__global__ void gn_stats_kernel(const float* x, float* gmean, float* grstd) {
    int bg = blockIdx.x;                       // 0..511, group data is contiguous
    const float* p = x + (size_t)bg * (CPG * HW);
    int t = threadIdx.x;
    float s = 0.f, ss = 0.f;
    for (int i = t; i < CPG * HW; i += 256) {
        float v = p[i];
        s += v; ss += v * v;
    }
    for (int o = 32; o; o >>= 1) { s += __shfl_down(s, o); ss += __shfl_down(ss, o); }
    __shared__ float as[4], ass[4];
    int w = t >> 6;
    if ((t & 63) == 0) { as[w] = s; ass[w] = ss; }
    __syncthreads();
    if (t == 0) {
        float S = as[0] + as[1] + as[2] + as[3];
        float SS = ass[0] + ass[1] + ass[2] + ass[3];
        float mean = S / (float)(CPG * HW);
        float var = SS / (float)(CPG * HW) - mean * mean;
        gmean[bg] = mean;
        grstd[bg] = rsqrtf(var + EPSV);
    }
}

// ---------------- GroupNorm pass 2: normalize + transpose to xn_t[b][p][c] bf16 --
__global__ void gn_apply_kernel(const float* x, const float* scale, const float* bias,
                                const float* gmean, const float* grstd,
                                unsigned short* xn_t) {
    int b = blockIdx.y;
    int p0 = blockIdx.x * 64;
    int t = threadIdx.x;
    __shared__ unsigned short lds[64][CH + 8];     // row stride 264*2B = 16B-aligned
    int pp = t & 63, cq = t >> 6;
    const float* xb = x + (size_t)b * CH * HW;
    for (int c0 = 0; c0 < CH; c0 += 4) {
        int c = c0 + cq;
        int g = b * NG + (c >> 3);
        float m = gmean[g], r = grstd[g];
        float v = xb[(size_t)c * HW + p0 + pp];
        lds[pp][c] = f2bf((v - m) * r * scale[c] + bias[c]);
    }
    __syncthreads();
    unsigned short* dst = xn_t + ((size_t)b * HW + p0) * CH;
    for (int pass = 0; pass < 4; pass++) {
        int row = pass * 16 + (t >> 4);
        int c = (t & 15) * 16;
        ulonglong2 v0 = *reinterpret_cast<ulonglong2*>(&lds[row][c]);
        ulonglong2 v1 = *reinterpret_cast<ulonglong2*>(&lds[row][c + 8]);
        *reinterpret_cast<ulonglong2*>(dst + (size_t)row * CH + c) = v0;
        *reinterpret_cast<ulonglong2*>(dst + (size_t)row * CH + c + 8) = v1;
    }
}

// ---------------- QKV GEMM: (16384 x 256) x (256 x 768), bf16 MFMA ---------------
__global__ __launch_bounds__(256) void qkv_kernel(const unsigned short* xn_t,
        const unsigned short* wqkv_t, const float* bqkv,
        unsigned short* qb, unsigned short* kb, unsigned short* vb) {
    int t = threadIdx.x;
    int wv = t >> 6, lane = t & 63, quad = lane >> 4, ln = lane & 15;
    int wr = wv >> 1, wc = wv & 1;
    int m0 = blockIdx.x * 128 + wr * 64;
    int n0 = blockIdx.y * 128 + wc * 64;

    f32x4 acc[4][4] = {};
    for (int k0 = 0; k0 < CH; k0 += 32) {
        int koff = k0 + quad * 8;
        bf16x8 af[4], bfr[4];
#pragma unroll
        for (int i = 0; i < 4; i++)
            af[i] = *reinterpret_cast<const bf16x8*>(xn_t + (size_t)(m0 + i * 16 + ln) * CH + koff);
#pragma unroll
        for (int j = 0; j < 4; j++)
            bfr[j] = *reinterpret_cast<const bf16x8*>(wqkv_t + (size_t)(n0 + j * 16 + ln) * CH + koff);
#pragma unroll
        for (int i = 0; i < 4; i++)
#pragma unroll
            for (int j = 0; j < 4; j++)
                acc[i][j] = __builtin_amdgcn_mfma_f32_16x16x32_bf16(af[i], bfr[j], acc[i][j], 0, 0, 0);
    }
#pragma unroll
    for (int j = 0; j < 4; j++) {
        int n = n0 + j * 16 + ln;
        float bias = bqkv[n];
        int which = n >> 8;              // uniform per 16-tile
        int dh_ = n & 255;
        int head = dh_ >> 6, d = dh_ & 63;
#pragma unroll
        for (int i = 0; i < 4; i++) {
            int mb = m0 + i * 16 + quad * 4;
            int bi = mb >> 10, p = mb & 1023;
            int bh = bi * NH + head;
            if (which < 2) {
                unsigned short* dst = (which == 0 ? qb : kb) + (size_t)bh * HW * DH;
                float sc = (which == 0) ? QSCALE : 1.0f;
#pragma unroll
                for (int r = 0; r < 4; r++)
                    dst[(size_t)(p + r) * DH + d] = f2bf((acc[i][j][r] + bias) * sc);
            } else {
                unsigned short* dst = vb + ((size_t)bh * DH + d) * HW + p;
                ushort4 pk4;
                pk4.x = f2bf(acc[i][j][0] + bias);
                pk4.y = f2bf(acc[i][j][1] + bias);
                pk4.z = f2bf(acc[i][j][2] + bias);
                pk4.w = f2bf(acc[i][j][3] + bias);
                *reinterpret_cast<ushort4*>(dst) = pk4;
            }
        }
    }
}

// ---------------- attention: LDS-staged K/V, 32 queries/wave ----------------------
// Block = 4 waves = 128 queries of one bh. Per 64-key iter: K tile (64x64 bf16)
// and V^T tile (64x64) staged once per block into LDS via global_load_lds
// (XOR-swizzled 16B chunks so ds_read_b128 fragments are ~conflict-free),
// double-buffered. Softmax: exp2 only (scale folded into Q), per-lane expsum
// reduced once at the end. P^T->B-layout via small per-wave LDS round-trip.
__global__ __launch_bounds__(256) void attn_kernel(const unsigned short* qb,
        const unsigned short* kb, const unsigned short* vb, unsigned short* h_t) {
    int qblk = blockIdx.x, bh = blockIdx.y;
    int t = threadIdx.x;
    int wv = t >> 6, lane = t & 63, quad = lane >> 4, ln = lane & 15;
    int q0 = qblk * 128 + wv * 32;

    const unsigned short* Q = qb + (size_t)bh * HW * DH;
    const unsigned short* K = kb + (size_t)bh * HW * DH;
    const unsigned short* V = vb + (size_t)bh * DH * HW;

    __shared__ __align__(16) unsigned short kbuf[2][4096];   // [p][swizzled 16B chunks]
    __shared__ __align__(16) unsigned short vbuf[2][4096];
    __shared__ __align__(16) unsigned short pbuf[4][2][16][72];

    // staging source indices: chunks c = c0 + lane; rows p = c>>3, chunk-in-row
    // stored at position (c&7), holding global chunk (c&7)^(p&7)
    int c_a = wv * 64 + lane;         // covers rows [wv*8, wv*8+8)
    int c_b = 256 + wv * 64 + lane;   // covers rows [32+wv*8, ...)
    int pa = c_a >> 3, ja = (c_a & 7) ^ (pa & 7);
    int pb = c_b >> 3, jb = (c_b & 7) ^ (pb & 7);
    const unsigned short* ksrc_a = K + (size_t)pa * DH + ja * 8;
    const unsigned short* ksrc_b = K + (size_t)pb * DH + jb * 8;
    const unsigned short* vsrc_a = V + (size_t)pa * HW + ja * 8;
    const unsigned short* vsrc_b = V + (size_t)pb * HW + jb * 8;
    int kofs_a = wv * 512, kofs_b = 2048 + wv * 512;

    bf16x8 qf[2][2];
#pragma unroll
    for (int nq = 0; nq < 2; nq++)
#pragma unroll
        for (int kk = 0; kk < 2; kk++)
            qf[nq][kk] = *reinterpret_cast<const bf16x8*>(
                Q + (size_t)(q0 + nq * 16 + ln) * DH + kk * 32 + quad * 8);

    f32x4 ls[2] = {};
    f32x4 o[2][4] = {};

    // prologue: stage tile 0 into buffer 0
    gld_lds16(ksrc_a, &kbuf[0][kofs_a]);
    gld_lds16(ksrc_b, &kbuf[0][kofs_b]);
    gld_lds16(vsrc_a, &vbuf[0][kofs_a]);
    gld_lds16(vsrc_b, &vbuf[0][kofs_b]);

    for (int it = 0; it < 16; it++) {
        int b = it & 1;
        __syncthreads();          // staging of buf b complete (barrier drains vmcnt)
        if (it < 15) {
            int k1 = (it + 1) * 64;
            gld_lds16(ksrc_a + (size_t)k1 * DH, &kbuf[b ^ 1][kofs_a]);
            gld_lds16(ksrc_b + (size_t)k1 * DH, &kbuf[b ^ 1][kofs_b]);
            gld_lds16(vsrc_a + k1, &vbuf[b ^ 1][kofs_a]);
            gld_lds16(vsrc_b + k1, &vbuf[b ^ 1][kofs_b]);
        }
        // fragment reads from LDS (swizzled)
        bf16x8 kf[4][2], vf[4][2];
#pragma unroll
        for (int mt = 0; mt < 4; mt++) {
            int p = mt * 16 + ln, sw = p & 7;
#pragma unroll
            for (int kk = 0; kk < 2; kk++) {
                int jj = (kk * 4 + quad) ^ sw;
                kf[mt][kk] = *reinterpret_cast<const bf16x8*>(&kbuf[b][p * 64 + jj * 8]);
                vf[mt][kk] = *reinterpret_cast<const bf16x8*>(&vbuf[b][p * 64 + jj * 8]);
            }
        }
#pragma unroll
        for (int nq = 0; nq < 2; nq++) {
            f32x4 s[4] = {};
#pragma unroll
            for (int mt = 0; mt < 4; mt++) {
                s[mt] = __builtin_amdgcn_mfma_f32_16x16x32_bf16(kf[mt][0], qf[nq][0], s[mt], 0, 0, 0);
                s[mt] = __builtin_amdgcn_mfma_f32_16x16x32_bf16(kf[mt][1], qf[nq][1], s[mt], 0, 0, 0);
            }
#pragma unroll
            for (int mt = 0; mt < 4; mt++) {
                ushort4 pk4;
                float e0 = exp2f(s[mt][0]); ls[nq][0] += e0; pk4.x = f2bf(e0);
                float e1 = exp2f(s[mt][1]); ls[nq][1] += e1; pk4.y = f2bf(e1);
                float e2 = exp2f(s[mt][2]); ls[nq][2] += e2; pk4.z = f2bf(e2);
                float e3 = exp2f(s[mt][3]); ls[nq][3] += e3; pk4.w = f2bf(e3);
                *reinterpret_cast<ushort4*>(&pbuf[wv][nq][ln][mt * 16 + quad * 4]) = pk4;
            }
#pragma unroll
            for (int kk = 0; kk < 2; kk++) {
                bf16x8 pf = *reinterpret_cast<const bf16x8*>(&pbuf[wv][nq][ln][kk * 32 + quad * 8]);
#pragma unroll
                for (int mt = 0; mt < 4; mt++)
                    o[nq][mt] = __builtin_amdgcn_mfma_f32_16x16x32_bf16(vf[mt][kk], pf, o[nq][mt], 0, 0, 0);
            }
        }
    }
    int b_ = bh >> 2, head = bh & 3;
#pragma unroll
    for (int nq = 0; nq < 2; nq++) {
        float lsum = ls[nq][0] + ls[nq][1] + ls[nq][2] + ls[nq][3];
        lsum += __shfl_xor(lsum, 16);
        lsum += __shfl_xor(lsum, 32);
        float inv = 1.0f / lsum;
        unsigned short* dst = h_t + ((size_t)b_ * HW + q0 + nq * 16 + ln) * CH + head * DH;
#pragma unroll
        for (int mt = 0; mt < 4; mt++) {
            ushort4 pk4;
            pk4.x = f2bf(o[nq][mt][0] * inv);
            pk4.y = f2bf(o[nq][mt][1] * inv);
            pk4.z = f2bf(o[nq][mt][2] * inv);
            pk4.w = f2bf(o[nq][mt][3] * inv);
            *reinterpret_cast<ushort4*>(dst + mt * 16 + quad * 4) = pk4;
        }
    }
}

// ---------------- proj GEMM + bias + residual + /sqrt(2) -------------------------
__global__ __launch_bounds__(256) void proj_kernel(const unsigned short* h_t,
        const unsigned short* wp_t, const float* bp, const float* x, float* out) {
    int t = threadIdx.x;
    int wv = t >> 6, lane = t & 63, quad = lane >> 4, ln = lane & 15;
    int wr = wv >> 1, wc = wv & 1;
    int m0 = blockIdx.x * 128 + wr * 64;
    int n0 = blockIdx.y * 128 + wc * 64;

    f32x4 acc[4][4] = {};
    for (int k0 = 0; k0 < CH; k0 += 32) {
        int koff = k0 + quad * 8;
        bf16x8 af[4], bfr[4];
#pragma unroll
        for (int i = 0; i < 4; i++)
            af[i] = *reinterpret_cast<const bf16x8*>(h_t + (size_t)(m0 + i * 16 + ln) * CH + koff);
#pragma unroll
        for (int j = 0; j < 4; j++)
            bfr[j] = *reinterpret_cast<const bf16x8*>(wp_t + (size_t)(n0 + j * 16 + ln) * CH + koff);
#pragma unroll
        for (int i = 0; i < 4; i++)
#pragma unroll
            for (int j = 0; j < 4; j++)
                acc[i][j] = __builtin_amdgcn_mfma_f32_16x16x32_bf16(af[i], bfr[j], acc[i][j], 0, 0, 0);
    }
    const float inv_s2 = 0.70710678118654752440f;
#pragma unroll
    for (int j = 0; j < 4; j++) {
        int n = n0 + j * 16 + ln;
        float bias = bp[n];
#pragma unroll
        for (int i = 0; i < 4; i++) {
            int mb = m0 + i * 16 + quad * 4;
            int bi = mb >> 10, p = mb & 1023;
            size_t off = ((size_t)(bi * CH + n)) * HW + p;
            float4 xv = *reinterpret_cast<const float4*>(x + off);
            float4 ov;
            ov.x = (xv.x + acc[i][j][0] + bias) * inv_s2;
            ov.y = (xv.y + acc[i][j][1] + bias) * inv_s2;
            ov.z = (xv.z + acc[i][j][2] + bias) * inv_s2;
            ov.w = (xv.w + acc[i][j][3] + bias) * inv_s2;
            *reinterpret_cast<float4*>(out + off) = ov;
        }
    }
}

extern "C" void kernel_launch(void* const* d_in, const int* in_sizes, int n_in,
                              void* d_out, int out_size, void* d_ws, size_t ws_size,
                              hipStream_t stream) {
    const float* x        = (const float*)d_in[0];
    const float* gn_scale = (const float*)d_in[1];
    const float* gn_bias  = (const float*)d_in[2];
    const float* Wq = (const float*)d_in[3];
    const float* bq = (const float*)d_in[4];
    const float* Wk = (const float*)d_in[5];
    const float* bk = (const float*)d_in[6];
    const float* Wv = (const float*)d_in[7];
    const float* bv = (const float*)d_in[8];
    const float* Wp = (const float*)d_in[9];
    const float* bp = (const float*)d_in[10];
    float* out = (float*)d_out;

    char* ws = (char*)d_ws;
    // ws layout (bytes); h_t aliases xn_t (xn_t dead after qkv_kernel). Total ~32.5 MB.
    float*          gmean  = (float*)(ws + 0);
    float*          grstd  = (float*)(ws + 2048);
    float*          bqkv   = (float*)(ws + 4096);
    unsigned short* wqkv_t = (unsigned short*)(ws + 8192);
    unsigned short* wp_t   = (unsigned short*)(ws + 401408);
    unsigned short* xn_t   = (unsigned short*)(ws + 532480);
    unsigned short* h_t    = xn_t;
    unsigned short* qb     = (unsigned short*)(ws + 8921088);
    unsigned short* kb     = (unsigned short*)(ws + 17309696);
    unsigned short* vb     = (unsigned short*)(ws + 25698304);

    prep_kernel<<<1024, 256, 0, stream>>>(Wq, Wk, Wv, Wp, bq, bk, bv, wqkv_t, wp_t, bqkv);
    gn_stats_kernel<<<512, 256, 0, stream>>>(x, gmean, grstd);
    gn_apply_kernel<<<dim3(16, 16), 256, 0, stream>>>(x, gn_scale, gn_bias, gmean, grstd, xn_t);
    qkv_kernel<<<dim3(128, 6), 256, 0, stream>>>(xn_t, wqkv_t, bqkv, qb, kb, vb);
    attn_kernel<<<dim3(8, 64), 256, 0, stream>>>(qb, kb, vb, h_t);
    proj_kernel<<<dim3(128, 2), 256, 0, stream>>>(h_t, wp_t, bp, x, out);
}

// Round 4
// 179.165 us; speedup vs baseline: 1.4805x; 1.0566x over previous
//
#include <hip/hip_runtime.h>
#include <hip/hip_bf16.h>

#define BATCH 16
#define CH    256
#define HW    1024
#define NH    4
#define DH    64
#define NG    32
#define CPG   8
#define EPSV  1e-6f

// log2(e) / sqrt(C) folded into Q so softmax = exp2(S_scaled)
#define QSCALE 0.090168440055558706f

typedef __bf16 bf16x8 __attribute__((ext_vector_type(8)));
typedef float  f32x4  __attribute__((ext_vector_type(4)));

__device__ __forceinline__ unsigned short f2bf(float f) {
    union { __hip_bfloat16 h; unsigned short u; } cv;
    cv.h = __float2bfloat16(f);
    return cv.u;
}

__device__ __forceinline__ unsigned int fbits(float f) {
    union { float f; unsigned int u; } cv; cv.f = f; return cv.u;
}

__device__ __forceinline__ void gld_lds16(const unsigned short* g, unsigned short* l) {
    __builtin_amdgcn_global_load_lds(
        (const __attribute__((address_space(1))) void*)g,
        (__attribute__((address_space(3))) void*)l, 16, 0, 0);
}

// ---------------- prep: weight transpose fp32[c][d] -> bf16[n][c], bias concat ----
__global__ void prep_kernel(const float* Wq, const float* Wk, const float* Wv,
                            const float* Wp, const float* bq, const float* bk,
                            const float* bv, unsigned short* wqkv_t,
                            unsigned short* wp_t, float* bqkv) {
    int idx = blockIdx.x * 256 + threadIdx.x;
    if (idx < 768 * 256) {
        int n = idx >> 8, c = idx & 255;
        const float* W = (n < 256) ? Wq : (n < 512) ? Wk : Wv;
        int d = n & 255;
        wqkv_t[idx] = f2bf(W[c * 256 + d]);
    } else if (idx < 768 * 256 + 256 * 256) {
        int j = idx - 768 * 256;
        int n = j >> 8, c = j & 255;
        wp_t[j] = f2bf(Wp[c * 256 + n]);
    }
    if (idx < 768)
        bqkv[idx] = (idx < 256) ? bq[idx] : (idx < 512) ? bk[idx - 256] : bv[idx - 512];
}

// ---------------- GroupNorm pass 1: per (b,g) mean/rstd --------------------------
__global__ void gn_stats_kernel(const float* x, float* gmean, float* grstd) {
    int bg = blockIdx.x;                       // 0..511, group data is contiguous
    const float* p = x + (size_t)bg * (CPG * HW);
    int t = threadIdx.x;
    float s = 0.f, ss = 0.f;
    for (int i = t; i < CPG * HW; i += 256) {
        float v = p[i];
        s += v; ss += v * v;
    }
    for (int o = 32; o; o >>= 1) { s += __shfl_down(s, o); ss += __shfl_down(ss, o); }
    __shared__ float as[4], ass[4];
    int w = t >> 6;
    if ((t & 63) == 0) { as[w] = s; ass[w] = ss; }
    __syncthreads();
    if (t == 0) {
        float S = as[0] + as[1] + as[2] + as[3];
        float SS = ass[0] + ass[1] + ass[2] + ass[3];
        float mean = S / (float)(CPG * HW);
        float var = SS / (float)(CPG * HW) - mean * mean;
        gmean[bg] = mean;
        grstd[bg] = rsqrtf(var + EPSV);
    }
}

// ---------------- GroupNorm pass 2: normalize + transpose to xn_t[b][p][c] bf16 --
__global__ void gn_apply_kernel(const float* x, const float* scale, const float* bias,
                                const float* gmean, const float* grstd,
                                unsigned short* xn_t) {
    int b = blockIdx.y;
    int p0 = blockIdx.x * 64;
    int t = threadIdx.x;
    __shared__ unsigned short lds[64][CH + 8];     // row stride 264*2B = 16B-aligned
    int pp = t & 63, cq = t >> 6;
    const float* xb = x + (size_t)b * CH * HW;
    for (int c0 = 0; c0 < CH; c0 += 4) {
        int c = c0 + cq;
        int g = b * NG + (c >> 3);
        float m = gmean[g], r = grstd[g];
        float v = xb[(size_t)c * HW + p0 + pp];
        lds[pp][c] = f2bf((v - m) * r * scale[c] + bias[c]);
    }
    __syncthreads();
    unsigned short* dst = xn_t + ((size_t)b * HW + p0) * CH;
    for (int pass = 0; pass < 4; pass++) {
        int row = pass * 16 + (t >> 4);
        int c = (t & 15) * 16;
        ulonglong2 v0 = *reinterpret_cast<ulonglong2*>(&lds[row][c]);
        ulonglong2 v1 = *reinterpret_cast<ulonglong2*>(&lds[row][c + 8]);
        *reinterpret_cast<ulonglong2*>(dst + (size_t)row * CH + c) = v0;
        *reinterpret_cast<ulonglong2*>(dst + (size_t)row * CH + c + 8) = v1;
    }
}

// ---------------- QKV GEMM: (16384 x 256) x (256 x 768), bf16 MFMA ---------------
__global__ __launch_bounds__(256) void qkv_kernel(const unsigned short* xn_t,
        const unsigned short* wqkv_t, const float* bqkv,
        unsigned short* qb, unsigned short* kb, unsigned short* vb) {
    int t = threadIdx.x;
    int wv = t >> 6, lane = t & 63, quad = lane >> 4, ln = lane & 15;
    int wr = wv >> 1, wc = wv & 1;
    int m0 = blockIdx.x * 128 + wr * 64;
    int n0 = blockIdx.y * 128 + wc * 64;

    f32x4 acc[4][4] = {};
    for (int k0 = 0; k0 < CH; k0 += 32) {
        int koff = k0 + quad * 8;
        bf16x8 af[4], bfr[4];
#pragma unroll
        for (int i = 0; i < 4; i++)
            af[i] = *reinterpret_cast<const bf16x8*>(xn_t + (size_t)(m0 + i * 16 + ln) * CH + koff);
#pragma unroll
        for (int j = 0; j < 4; j++)
            bfr[j] = *reinterpret_cast<const bf16x8*>(wqkv_t + (size_t)(n0 + j * 16 + ln) * CH + koff);
#pragma unroll
        for (int i = 0; i < 4; i++)
#pragma unroll
            for (int j = 0; j < 4; j++)
                acc[i][j] = __builtin_amdgcn_mfma_f32_16x16x32_bf16(af[i], bfr[j], acc[i][j], 0, 0, 0);
    }
#pragma unroll
    for (int j = 0; j < 4; j++) {
        int n = n0 + j * 16 + ln;
        float bias = bqkv[n];
        int which = n >> 8;              // uniform per 16-tile
        int dh_ = n & 255;
        int head = dh_ >> 6, d = dh_ & 63;
#pragma unroll
        for (int i = 0; i < 4; i++) {
            int mb = m0 + i * 16 + quad * 4;
            int bi = mb >> 10, p = mb & 1023;
            int bh = bi * NH + head;
            if (which < 2) {
                unsigned short* dst = (which == 0 ? qb : kb) + (size_t)bh * HW * DH;
                float sc = (which == 0) ? QSCALE : 1.0f;
#pragma unroll
                for (int r = 0; r < 4; r++)
                    dst[(size_t)(p + r) * DH + d] = f2bf((acc[i][j][r] + bias) * sc);
            } else {
                unsigned short* dst = vb + ((size_t)bh * DH + d) * HW + p;
                ushort4 pk4;
                pk4.x = f2bf(acc[i][j][0] + bias);
                pk4.y = f2bf(acc[i][j][1] + bias);
                pk4.z = f2bf(acc[i][j][2] + bias);
                pk4.w = f2bf(acc[i][j][3] + bias);
                *reinterpret_cast<ushort4*>(dst) = pk4;
            }
        }
    }
}

// ---------------- attention: LDS-staged K/V, 32 q/wave, unroll-2 pipeline ---------
__global__ __launch_bounds__(256) void attn_kernel(const unsigned short* qb,
        const unsigned short* kb, const unsigned short* vb, unsigned short* h_t) {
    int qblk = blockIdx.x, bh = blockIdx.y;
    int t = threadIdx.x;
    int wv = t >> 6, lane = t & 63, quad = lane >> 4, ln = lane & 15;
    int q0 = qblk * 128 + wv * 32;

    const unsigned short* Q = qb + (size_t)bh * HW * DH;
    const unsigned short* K = kb + (size_t)bh * HW * DH;
    const unsigned short* V = vb + (size_t)bh * DH * HW;

    __shared__ __align__(16) unsigned short kbuf[2][4096];   // [p][swizzled 16B chunks]
    __shared__ __align__(16) unsigned short vbuf[2][4096];
    __shared__ __align__(16) unsigned short pbuf[4][2][16][72];

    // staging: chunk c -> row p = c>>3, stored slot (c&7), holding global chunk (c&7)^(p&7)
    int c_a = wv * 64 + lane;
    int c_b = 256 + wv * 64 + lane;
    int pa = c_a >> 3, ja = (c_a & 7) ^ (pa & 7);
    int pb = c_b >> 3, jb = (c_b & 7) ^ (pb & 7);
    const unsigned short* pka = K + (size_t)pa * DH + ja * 8;
    const unsigned short* pkb = K + (size_t)pb * DH + jb * 8;
    const unsigned short* pva = V + (size_t)pa * HW + ja * 8;
    const unsigned short* pvb = V + (size_t)pb * HW + jb * 8;
    int lofs_a = wv * 512, lofs_b = 2048 + wv * 512;

    // loop-invariant LDS fragment offsets (ushort units)
    int koffs[4][2];
#pragma unroll
    for (int mt = 0; mt < 4; mt++) {
        int p = mt * 16 + ln, sw = p & 7;
#pragma unroll
        for (int kk = 0; kk < 2; kk++)
            koffs[mt][kk] = p * 64 + (((kk * 4 + quad) ^ sw) * 8);
    }

    bf16x8 qf[2][2];
#pragma unroll
    for (int nq = 0; nq < 2; nq++)
#pragma unroll
        for (int kk = 0; kk < 2; kk++)
            qf[nq][kk] = *reinterpret_cast<const bf16x8*>(
                Q + (size_t)(q0 + nq * 16 + ln) * DH + kk * 32 + quad * 8);

    f32x4 ls[2] = {};
    f32x4 o[2][4] = {};

    // prologue: stage tile 0 into buffer 0
    gld_lds16(pka, &kbuf[0][lofs_a]);
    gld_lds16(pkb, &kbuf[0][lofs_b]);
    gld_lds16(pva, &vbuf[0][lofs_a]);
    gld_lds16(pvb, &vbuf[0][lofs_b]);
    pka += 64 * DH; pkb += 64 * DH; pva += 64; pvb += 64;

    // one unrolled iteration: stage next tile into buf (B^1), compute from buf B
#define ATTN_TILE(B, DO_STAGE)                                                      \
    {                                                                               \
        __syncthreads();                                                            \
        if (DO_STAGE) {                                                             \
            gld_lds16(pka, &kbuf[B ^ 1][lofs_a]);                                   \
            gld_lds16(pkb, &kbuf[B ^ 1][lofs_b]);                                   \
            gld_lds16(pva, &vbuf[B ^ 1][lofs_a]);                                   \
            gld_lds16(pvb, &vbuf[B ^ 1][lofs_b]);                                   \
            pka += 64 * DH; pkb += 64 * DH; pva += 64; pvb += 64;                   \
        }                                                                           \
        bf16x8 kf[4][2], vf[4][2];                                                  \
        _Pragma("unroll")                                                           \
        for (int mt = 0; mt < 4; mt++) {                                            \
            _Pragma("unroll")                                                       \
            for (int kk = 0; kk < 2; kk++) {                                        \
                kf[mt][kk] = *reinterpret_cast<const bf16x8*>(&kbuf[B][koffs[mt][kk]]); \
                vf[mt][kk] = *reinterpret_cast<const bf16x8*>(&vbuf[B][koffs[mt][kk]]); \
            }                                                                       \
        }                                                                           \
        f32x4 s[2][4] = {};                                                         \
        _Pragma("unroll")                                                           \
        for (int nq = 0; nq < 2; nq++)                                              \
            _Pragma("unroll")                                                       \
            for (int mt = 0; mt < 4; mt++) {                                        \
                s[nq][mt] = __builtin_amdgcn_mfma_f32_16x16x32_bf16(kf[mt][0], qf[nq][0], s[nq][mt], 0, 0, 0); \
                s[nq][mt] = __builtin_amdgcn_mfma_f32_16x16x32_bf16(kf[mt][1], qf[nq][1], s[nq][mt], 0, 0, 0); \
            }                                                                       \
        _Pragma("unroll")                                                           \
        for (int nq = 0; nq < 2; nq++)                                              \
            _Pragma("unroll")                                                       \
            for (int mt = 0; mt < 4; mt++) {                                        \
                float e0 = __builtin_amdgcn_exp2f(s[nq][mt][0]);                    \
                float e1 = __builtin_amdgcn_exp2f(s[nq][mt][1]);                    \
                float e2 = __builtin_amdgcn_exp2f(s[nq][mt][2]);                    \
                float e3 = __builtin_amdgcn_exp2f(s[nq][mt][3]);                    \
                ls[nq][0] += e0; ls[nq][1] += e1;                                   \
                ls[nq][2] += e2; ls[nq][3] += e3;                                   \
                uint2 pk2;                                                          \
                pk2.x = __builtin_amdgcn_perm(fbits(e1), fbits(e0), 0x07060302u);   \
                pk2.y = __builtin_amdgcn_perm(fbits(e3), fbits(e2), 0x07060302u);   \
                *reinterpret_cast<uint2*>(&pbuf[wv][nq][ln][mt * 16 + quad * 4]) = pk2; \
            }                                                                       \
        _Pragma("unroll")                                                           \
        for (int nq = 0; nq < 2; nq++)                                              \
            _Pragma("unroll")                                                       \
            for (int kk = 0; kk < 2; kk++) {                                        \
                bf16x8 pf = *reinterpret_cast<const bf16x8*>(&pbuf[wv][nq][ln][kk * 32 + quad * 8]); \
                _Pragma("unroll")                                                   \
                for (int mt = 0; mt < 4; mt++)                                      \
                    o[nq][mt] = __builtin_amdgcn_mfma_f32_16x16x32_bf16(vf[mt][kk], pf, o[nq][mt], 0, 0, 0); \
            }                                                                       \
    }

    for (int u = 0; u < 8; u++) {
        ATTN_TILE(0, true)            // compute tile 2u,   stage tile 2u+1
        ATTN_TILE(1, (u < 7))         // compute tile 2u+1, stage tile 2u+2
    }
#undef ATTN_TILE

    int b_ = bh >> 2, head = bh & 3;
#pragma unroll
    for (int nq = 0; nq < 2; nq++) {
        float lsum = ls[nq][0] + ls[nq][1] + ls[nq][2] + ls[nq][3];
        lsum += __shfl_xor(lsum, 16);
        lsum += __shfl_xor(lsum, 32);
        float inv = 1.0f / lsum;
        unsigned short* dst = h_t + ((size_t)b_ * HW + q0 + nq * 16 + ln) * CH + head * DH;
#pragma unroll
        for (int mt = 0; mt < 4; mt++) {
            ushort4 pk4;
            pk4.x = f2bf(o[nq][mt][0] * inv);
            pk4.y = f2bf(o[nq][mt][1] * inv);
            pk4.z = f2bf(o[nq][mt][2] * inv);
            pk4.w = f2bf(o[nq][mt][3] * inv);
            *reinterpret_cast<ushort4*>(dst + mt * 16 + quad * 4) = pk4;
        }
    }
}

// ---------------- proj GEMM + bias + residual + /sqrt(2) -------------------------
__global__ __launch_bounds__(256) void proj_kernel(const unsigned short* h_t,
        const unsigned short* wp_t, const float* bp, const float* x, float* out) {
    int t = threadIdx.x;
    int wv = t >> 6, lane = t & 63, quad = lane >> 4, ln = lane & 15;
    int wr = wv >> 1, wc = wv & 1;
    int m0 = blockIdx.x * 128 + wr * 64;
    int n0 = blockIdx.y * 128 + wc * 64;

    f32x4 acc[4][4] = {};
    for (int k0 = 0; k0 < CH; k0 += 32) {
        int koff = k0 + quad * 8;
        bf16x8 af[4], bfr[4];
#pragma unroll
        for (int i = 0; i < 4; i++)
            af[i] = *reinterpret_cast<const bf16x8*>(h_t + (size_t)(m0 + i * 16 + ln) * CH + koff);
#pragma unroll
        for (int j = 0; j < 4; j++)
            bfr[j] = *reinterpret_cast<const bf16x8*>(wp_t + (size_t)(n0 + j * 16 + ln) * CH + koff);
#pragma unroll
        for (int i = 0; i < 4; i++)
#pragma unroll
            for (int j = 0; j < 4; j++)
                acc[i][j] = __builtin_amdgcn_mfma_f32_16x16x32_bf16(af[i], bfr[j], acc[i][j], 0, 0, 0);
    }
    const float inv_s2 = 0.70710678118654752440f;
#pragma unroll
    for (int j = 0; j < 4; j++) {
        int n = n0 + j * 16 + ln;
        float bias = bp[n];
#pragma unroll
        for (int i = 0; i < 4; i++) {
            int mb = m0 + i * 16 + quad * 4;
            int bi = mb >> 10, p = mb & 1023;
            size_t off = ((size_t)(bi * CH + n)) * HW + p;
            float4 xv = *reinterpret_cast<const float4*>(x + off);
            float4 ov;
            ov.x = (xv.x + acc[i][j][0] + bias) * inv_s2;
            ov.y = (xv.y + acc[i][j][1] + bias) * inv_s2;
            ov.z = (xv.z + acc[i][j][2] + bias) * inv_s2;
            ov.w = (xv.w + acc[i][j][3] + bias) * inv_s2;
            *reinterpret_cast<float4*>(out + off) = ov;
        }
    }
}

extern "C" void kernel_launch(void* const* d_in, const int* in_sizes, int n_in,
                              void* d_out, int out_size, void* d_ws, size_t ws_size,
                              hipStream_t stream) {
    const float* x        = (const float*)d_in[0];
    const float* gn_scale = (const float*)d_in[1];
    const float* gn_bias  = (const float*)d_in[2];
    const float* Wq = (const float*)d_in[3];
    const float* bq = (const float*)d_in[4];
    const float* Wk = (const float*)d_in[5];
    const float* bk = (const float*)d_in[6];
    const float* Wv = (const float*)d_in[7];
    const float* bv = (const float*)d_in[8];
    const float* Wp = (const float*)d_in[9];
    const float* bp = (const float*)d_in[10];
    float* out = (float*)d_out;

    char* ws = (char*)d_ws;
    // ws layout (bytes); h_t aliases xn_t (xn_t dead after qkv_kernel). Total ~32.5 MB.
    float*          gmean  = (float*)(ws + 0);
    float*          grstd  = (float*)(ws + 2048);
    float*          bqkv   = (float*)(ws + 4096);
    unsigned short* wqkv_t = (unsigned short*)(ws + 8192);
    unsigned short* wp_t   = (unsigned short*)(ws + 401408);
    unsigned short* xn_t   = (unsigned short*)(ws + 532480);
    unsigned short* h_t    = xn_t;
    unsigned short* qb     = (unsigned short*)(ws + 8921088);
    unsigned short* kb     = (unsigned short*)(ws + 17309696);
    unsigned short* vb     = (unsigned short*)(ws + 25698304);

    prep_kernel<<<1024, 256, 0, stream>>>(Wq, Wk, Wv, Wp, bq, bk, bv, wqkv_t, wp_t, bqkv);
    gn_stats_kernel<<<512, 256, 0, stream>>>(x, gmean, grstd);
    gn_apply_kernel<<<dim3(16, 16), 256, 0, stream>>>(x, gn_scale, gn_bias, gmean, grstd, xn_t);
    qkv_kernel<<<dim3(128, 6), 256, 0, stream>>>(xn_t, wqkv_t, bqkv, qb, kb, vb);
    attn_kernel<<<dim3(8, 64), 256, 0, stream>>>(qb, kb, vb, h_t);
    proj_kernel<<<dim3(128, 2), 256, 0, stream>>>(h_t, wp_t, bp, x, out);
}

// Round 5
// 162.337 us; speedup vs baseline: 1.6339x; 1.1037x over previous
//
#include <hip/hip_runtime.h>
#include <hip/hip_bf16.h>

#define BATCH 16
#define CH    256
#define HW    1024
#define NH    4
#define DH    64
#define NG    32
#define CPG   8
#define EPSV  1e-6f

// log2(e) / sqrt(C) folded into Q so softmax = exp2(S_scaled)
#define QSCALE 0.090168440055558706f

typedef __bf16 bf16x8 __attribute__((ext_vector_type(8)));
typedef float  f32x4  __attribute__((ext_vector_type(4)));

__device__ __forceinline__ unsigned short f2bf(float f) {
    union { __hip_bfloat16 h; unsigned short u; } cv;
    cv.h = __float2bfloat16(f);
    return cv.u;
}

__device__ __forceinline__ unsigned int fbits(float f) {
    union { float f; unsigned int u; } cv; cv.f = f; return cv.u;
}

__device__ __forceinline__ void gld_lds16(const unsigned short* g, unsigned short* l) {
    __builtin_amdgcn_global_load_lds(
        (const __attribute__((address_space(1))) void*)g,
        (__attribute__((address_space(3))) void*)l, 16, 0, 0);
}

// ---------------- prep: weight transpose fp32[c][d] -> bf16[n][c], bias concat ----
__global__ void prep_kernel(const float* Wq, const float* Wk, const float* Wv,
                            const float* Wp, const float* bq, const float* bk,
                            const float* bv, unsigned short* wqkv_t,
                            unsigned short* wp_t, float* bqkv) {
    int idx = blockIdx.x * 256 + threadIdx.x;
    if (idx < 768 * 256) {
        int n = idx >> 8, c = idx & 255;
        const float* W = (n < 256) ? Wq : (n < 512) ? Wk : Wv;
        int d = n & 255;
        wqkv_t[idx] = f2bf(W[c * 256 + d]);
    } else if (idx < 768 * 256 + 256 * 256) {
        int j = idx - 768 * 256;
        int n = j >> 8, c = j & 255;
        wp_t[j] = f2bf(Wp[c * 256 + n]);
    }
    if (idx < 768)
        bqkv[idx] = (idx < 256) ? bq[idx] : (idx < 512) ? bk[idx - 256] : bv[idx - 512];
}

// ---------------- GroupNorm stats -> per-channel affine coefs --------------------
// coefA[b][c] = rstd*scale[c]; coefB[b][c] = bias[c] - mean*rstd*scale[c]
__global__ void gn_stats_kernel(const float* x, const float* scale, const float* bias,
                                float* coefA, float* coefB) {
    int bg = blockIdx.x;                       // b*32+g, group data contiguous
    const float4* p = reinterpret_cast<const float4*>(x + (size_t)bg * (CPG * HW));
    int t = threadIdx.x;
    float s = 0.f, ss = 0.f;
    for (int i = t; i < CPG * HW / 4; i += 256) {
        float4 v = p[i];
        s += v.x + v.y + v.z + v.w;
        ss += v.x * v.x + v.y * v.y + v.z * v.z + v.w * v.w;
    }
    for (int o = 32; o; o >>= 1) { s += __shfl_down(s, o); ss += __shfl_down(ss, o); }
    __shared__ float as[4], ass[4];
    int w = t >> 6;
    if ((t & 63) == 0) { as[w] = s; ass[w] = ss; }
    __syncthreads();
    if (t < 8) {
        float S = as[0] + as[1] + as[2] + as[3];
        float SS = ass[0] + ass[1] + ass[2] + ass[3];
        float mean = S / (float)(CPG * HW);
        float var = SS / (float)(CPG * HW) - mean * mean;
        float rstd = rsqrtf(var + EPSV);
        int b = bg >> 5, g = bg & 31;
        int c = g * CPG + t;
        float a = rstd * scale[c];
        coefA[b * CH + c] = a;
        coefB[b * CH + c] = bias[c] - mean * a;
    }
}

// ---------------- QKV GEMM with fused GroupNorm-apply ----------------------------
// A-tile (128 p x 32 c) built in LDS from x directly: coalesced fp32 loads along p,
// fmaf normalize, RNE pair-pack to bf16, 16B slots XOR-swizzled by (p&3).
// B = wqkv_t[n][k] direct from global (L2-resident weights).
__global__ __launch_bounds__(256) void qkv_kernel(const float* x,
        const float* coefA, const float* coefB,
        const unsigned short* wqkv_t, const float* bqkv,
        unsigned short* qb, unsigned short* kb, unsigned short* vb) {
    int t = threadIdx.x;
    int wv = t >> 6, lane = t & 63, quad = lane >> 4, ln = lane & 15;
    int wr = wv >> 1, wc = wv & 1;
    int bx = blockIdx.x;
    int m0 = bx * 128 + wr * 64;          // global m for epilogue
    int n0 = blockIdx.y * 128 + wc * 64;
    int bb = bx >> 3;                     // batch
    int p0 = (bx & 7) * 128;              // spatial base

    __shared__ __align__(16) unsigned short lds_a[128][40];  // 80B row stride, 16B-aligned

    const float* xb = x + (size_t)bb * CH * HW + p0;
    const float* cA = coefA + bb * CH;
    const float* cB = coefB + bb * CH;

    int sp = t & 127;                     // p within tile
    int sbase = (t >> 7) * 2;             // slot base (0 or 2)

    f32x4 acc[4][4] = {};
    for (int k0 = 0; k0 < CH; k0 += 32) {
        bf16x8 wpk[2];
#pragma unroll
        for (int rep = 0; rep < 2; rep++) {
            int s = sbase + rep;
            int cb = k0 + s * 8;
            union { bf16x8 v8; __hip_bfloat162 h2[4]; } u;
#pragma unroll
            for (int j = 0; j < 4; j++) {
                float v0 = fmaf(xb[(size_t)(cb + 2 * j)     * HW + sp], cA[cb + 2 * j],     cB[cb + 2 * j]);
                float v1 = fmaf(xb[(size_t)(cb + 2 * j + 1) * HW + sp], cA[cb + 2 * j + 1], cB[cb + 2 * j + 1]);
                u.h2[j] = __float22bfloat162_rn(float2{v0, v1});
            }
            wpk[rep] = u.v8;
        }
        __syncthreads();                  // previous iter's fragment reads done
#pragma unroll
        for (int rep = 0; rep < 2; rep++) {
            int s = sbase + rep;
            int phys = s ^ (sp & 3);
            *reinterpret_cast<bf16x8*>(&lds_a[sp][phys * 8]) = wpk[rep];
        }
        __syncthreads();                  // tile visible
        bf16x8 af[4], bfr[4];
#pragma unroll
        for (int i = 0; i < 4; i++) {
            int p = wr * 64 + i * 16 + ln;
            af[i] = *reinterpret_cast<const bf16x8*>(&lds_a[p][(quad ^ (p & 3)) * 8]);
        }
#pragma unroll
        for (int j = 0; j < 4; j++)
            bfr[j] = *reinterpret_cast<const bf16x8*>(
                wqkv_t + (size_t)(n0 + j * 16 + ln) * CH + k0 + quad * 8);
#pragma unroll
        for (int i = 0; i < 4; i++)
#pragma unroll
            for (int j = 0; j < 4; j++)
                acc[i][j] = __builtin_amdgcn_mfma_f32_16x16x32_bf16(af[i], bfr[j], acc[i][j], 0, 0, 0);
    }
#pragma unroll
    for (int j = 0; j < 4; j++) {
        int n = n0 + j * 16 + ln;
        float bias = bqkv[n];
        int which = n >> 8;               // uniform per 16-tile
        int dh_ = n & 255;
        int head = dh_ >> 6, d = dh_ & 63;
#pragma unroll
        for (int i = 0; i < 4; i++) {
            int mb = m0 + i * 16 + quad * 4;
            int bi = mb >> 10, p = mb & 1023;
            int bh = bi * NH + head;
            if (which < 2) {
                unsigned short* dst = (which == 0 ? qb : kb) + (size_t)bh * HW * DH;
                float sc = (which == 0) ? QSCALE : 1.0f;
#pragma unroll
                for (int r = 0; r < 4; r++)
                    dst[(size_t)(p + r) * DH + d] = f2bf((acc[i][j][r] + bias) * sc);
            } else {
                unsigned short* dst = vb + ((size_t)bh * DH + d) * HW + p;
                ushort4 pk4;
                pk4.x = f2bf(acc[i][j][0] + bias);
                pk4.y = f2bf(acc[i][j][1] + bias);
                pk4.z = f2bf(acc[i][j][2] + bias);
                pk4.w = f2bf(acc[i][j][3] + bias);
                *reinterpret_cast<ushort4*>(dst) = pk4;
            }
        }
    }
}

// ---------------- attention: LDS-staged K/V, 32 q/wave, unroll-2 pipeline ---------
__global__ __launch_bounds__(256) void attn_kernel(const unsigned short* qb,
        const unsigned short* kb, const unsigned short* vb, unsigned short* h_t) {
    int qblk = blockIdx.x, bh = blockIdx.y;
    int t = threadIdx.x;
    int wv = t >> 6, lane = t & 63, quad = lane >> 4, ln = lane & 15;
    int q0 = qblk * 128 + wv * 32;

    const unsigned short* Q = qb + (size_t)bh * HW * DH;
    const unsigned short* K = kb + (size_t)bh * HW * DH;
    const unsigned short* V = vb + (size_t)bh * DH * HW;

    __shared__ __align__(16) unsigned short kbuf[2][4096];   // [p][swizzled 16B chunks]
    __shared__ __align__(16) unsigned short vbuf[2][4096];
    __shared__ __align__(16) unsigned short pbuf[4][2][16][72];

    // staging: chunk c -> row p = c>>3, stored slot (c&7), holding global chunk (c&7)^(p&7)
    int c_a = wv * 64 + lane;
    int c_b = 256 + wv * 64 + lane;
    int pa = c_a >> 3, ja = (c_a & 7) ^ (pa & 7);
    int pb = c_b >> 3, jb = (c_b & 7) ^ (pb & 7);
    const unsigned short* pka = K + (size_t)pa * DH + ja * 8;
    const unsigned short* pkb = K + (size_t)pb * DH + jb * 8;
    const unsigned short* pva = V + (size_t)pa * HW + ja * 8;
    const unsigned short* pvb = V + (size_t)pb * HW + jb * 8;
    int lofs_a = wv * 512, lofs_b = 2048 + wv * 512;

    // loop-invariant LDS fragment offsets (ushort units)
    int koffs[4][2];
#pragma unroll
    for (int mt = 0; mt < 4; mt++) {
        int p = mt * 16 + ln, sw = p & 7;
#pragma unroll
        for (int kk = 0; kk < 2; kk++)
            koffs[mt][kk] = p * 64 + (((kk * 4 + quad) ^ sw) * 8);
    }

    bf16x8 qf[2][2];
#pragma unroll
    for (int nq = 0; nq < 2; nq++)
#pragma unroll
        for (int kk = 0; kk < 2; kk++)
            qf[nq][kk] = *reinterpret_cast<const bf16x8*>(
                Q + (size_t)(q0 + nq * 16 + ln) * DH + kk * 32 + quad * 8);

    f32x4 ls[2] = {};
    f32x4 o[2][4] = {};

    // prologue: stage tile 0 into buffer 0
    gld_lds16(pka, &kbuf[0][lofs_a]);
    gld_lds16(pkb, &kbuf[0][lofs_b]);
    gld_lds16(pva, &vbuf[0][lofs_a]);
    gld_lds16(pvb, &vbuf[0][lofs_b]);
    pka += 64 * DH; pkb += 64 * DH; pva += 64; pvb += 64;

#define ATTN_TILE(B, DO_STAGE)                                                      \
    {                                                                               \
        __syncthreads();                                                            \
        if (DO_STAGE) {                                                             \
            gld_lds16(pka, &kbuf[B ^ 1][lofs_a]);                                   \
            gld_lds16(pkb, &kbuf[B ^ 1][lofs_b]);                                   \
            gld_lds16(pva, &vbuf[B ^ 1][lofs_a]);                                   \
            gld_lds16(pvb, &vbuf[B ^ 1][lofs_b]);                                   \
            pka += 64 * DH; pkb += 64 * DH; pva += 64; pvb += 64;                   \
        }                                                                           \
        bf16x8 kf[4][2], vf[4][2];                                                  \
        _Pragma("unroll")                                                           \
        for (int mt = 0; mt < 4; mt++) {                                            \
            _Pragma("unroll")                                                       \
            for (int kk = 0; kk < 2; kk++) {                                        \
                kf[mt][kk] = *reinterpret_cast<const bf16x8*>(&kbuf[B][koffs[mt][kk]]); \
                vf[mt][kk] = *reinterpret_cast<const bf16x8*>(&vbuf[B][koffs[mt][kk]]); \
            }                                                                       \
        }                                                                           \
        f32x4 s[2][4] = {};                                                         \
        _Pragma("unroll")                                                           \
        for (int nq = 0; nq < 2; nq++)                                              \
            _Pragma("unroll")                                                       \
            for (int mt = 0; mt < 4; mt++) {                                        \
                s[nq][mt] = __builtin_amdgcn_mfma_f32_16x16x32_bf16(kf[mt][0], qf[nq][0], s[nq][mt], 0, 0, 0); \
                s[nq][mt] = __builtin_amdgcn_mfma_f32_16x16x32_bf16(kf[mt][1], qf[nq][1], s[nq][mt], 0, 0, 0); \
            }                                                                       \
        _Pragma("unroll")                                                           \
        for (int nq = 0; nq < 2; nq++)                                              \
            _Pragma("unroll")                                                       \
            for (int mt = 0; mt < 4; mt++) {                                        \
                float e0 = __builtin_amdgcn_exp2f(s[nq][mt][0]);                    \
                float e1 = __builtin_amdgcn_exp2f(s[nq][mt][1]);                    \
                float e2 = __builtin_amdgcn_exp2f(s[nq][mt][2]);                    \
                float e3 = __builtin_amdgcn_exp2f(s[nq][mt][3]);                    \
                ls[nq][0] += e0; ls[nq][1] += e1;                                   \
                ls[nq][2] += e2; ls[nq][3] += e3;                                   \
                uint2 pk2;                                                          \
                pk2.x = __builtin_amdgcn_perm(fbits(e1), fbits(e0), 0x07060302u);   \
                pk2.y = __builtin_amdgcn_perm(fbits(e3), fbits(e2), 0x07060302u);   \
                *reinterpret_cast<uint2*>(&pbuf[wv][nq][ln][mt * 16 + quad * 4]) = pk2; \
            }                                                                       \
        _Pragma("unroll")                                                           \
        for (int nq = 0; nq < 2; nq++)                                              \
            _Pragma("unroll")                                                       \
            for (int kk = 0; kk < 2; kk++) {                                        \
                bf16x8 pf = *reinterpret_cast<const bf16x8*>(&pbuf[wv][nq][ln][kk * 32 + quad * 8]); \
                _Pragma("unroll")                                                   \
                for (int mt = 0; mt < 4; mt++)                                      \
                    o[nq][mt] = __builtin_amdgcn_mfma_f32_16x16x32_bf16(vf[mt][kk], pf, o[nq][mt], 0, 0, 0); \
            }                                                                       \
    }

    for (int u = 0; u < 8; u++) {
        ATTN_TILE(0, true)            // compute tile 2u,   stage tile 2u+1
        ATTN_TILE(1, (u < 7))         // compute tile 2u+1, stage tile 2u+2
    }
#undef ATTN_TILE

    int b_ = bh >> 2, head = bh & 3;
#pragma unroll
    for (int nq = 0; nq < 2; nq++) {
        float lsum = ls[nq][0] + ls[nq][1] + ls[nq][2] + ls[nq][3];
        lsum += __shfl_xor(lsum, 16);
        lsum += __shfl_xor(lsum, 32);
        float inv = 1.0f / lsum;
        unsigned short* dst = h_t + ((size_t)b_ * HW + q0 + nq * 16 + ln) * CH + head * DH;
#pragma unroll
        for (int mt = 0; mt < 4; mt++) {
            ushort4 pk4;
            pk4.x = f2bf(o[nq][mt][0] * inv);
            pk4.y = f2bf(o[nq][mt][1] * inv);
            pk4.z = f2bf(o[nq][mt][2] * inv);
            pk4.w = f2bf(o[nq][mt][3] * inv);
            *reinterpret_cast<ushort4*>(dst + mt * 16 + quad * 4) = pk4;
        }
    }
}

// ---------------- proj GEMM + bias + residual + /sqrt(2) -------------------------
// 64x128 block tile (512 blocks -> 2 blocks/CU), 32x64 per wave.
__global__ __launch_bounds__(256) void proj_kernel(const unsigned short* h_t,
        const unsigned short* wp_t, const float* bp, const float* x, float* out) {
    int t = threadIdx.x;
    int wv = t >> 6, lane = t & 63, quad = lane >> 4, ln = lane & 15;
    int wr = wv >> 1, wc = wv & 1;
    int m0 = blockIdx.x * 64 + wr * 32;
    int n0 = blockIdx.y * 128 + wc * 64;

    f32x4 acc[2][4] = {};
    for (int k0 = 0; k0 < CH; k0 += 32) {
        int koff = k0 + quad * 8;
        bf16x8 af[2], bfr[4];
#pragma unroll
        for (int i = 0; i < 2; i++)
            af[i] = *reinterpret_cast<const bf16x8*>(h_t + (size_t)(m0 + i * 16 + ln) * CH + koff);
#pragma unroll
        for (int j = 0; j < 4; j++)
            bfr[j] = *reinterpret_cast<const bf16x8*>(wp_t + (size_t)(n0 + j * 16 + ln) * CH + koff);
#pragma unroll
        for (int i = 0; i < 2; i++)
#pragma unroll
            for (int j = 0; j < 4; j++)
                acc[i][j] = __builtin_amdgcn_mfma_f32_16x16x32_bf16(af[i], bfr[j], acc[i][j], 0, 0, 0);
    }
    const float inv_s2 = 0.70710678118654752440f;
#pragma unroll
    for (int j = 0; j < 4; j++) {
        int n = n0 + j * 16 + ln;
        float bias = bp[n];
#pragma unroll
        for (int i = 0; i < 2; i++) {
            int mb = m0 + i * 16 + quad * 4;
            int bi = mb >> 10, p = mb & 1023;
            size_t off = ((size_t)(bi * CH + n)) * HW + p;
            float4 xv = *reinterpret_cast<const float4*>(x + off);
            float4 ov;
            ov.x = (xv.x + acc[i][j][0] + bias) * inv_s2;
            ov.y = (xv.y + acc[i][j][1] + bias) * inv_s2;
            ov.z = (xv.z + acc[i][j][2] + bias) * inv_s2;
            ov.w = (xv.w + acc[i][j][3] + bias) * inv_s2;
            *reinterpret_cast<float4*>(out + off) = ov;
        }
    }
}

extern "C" void kernel_launch(void* const* d_in, const int* in_sizes, int n_in,
                              void* d_out, int out_size, void* d_ws, size_t ws_size,
                              hipStream_t stream) {
    const float* x        = (const float*)d_in[0];
    const float* gn_scale = (const float*)d_in[1];
    const float* gn_bias  = (const float*)d_in[2];
    const float* Wq = (const float*)d_in[3];
    const float* bq = (const float*)d_in[4];
    const float* Wk = (const float*)d_in[5];
    const float* bk = (const float*)d_in[6];
    const float* Wv = (const float*)d_in[7];
    const float* bv = (const float*)d_in[8];
    const float* Wp = (const float*)d_in[9];
    const float* bp = (const float*)d_in[10];
    float* out = (float*)d_out;

    char* ws = (char*)d_ws;
    // ws layout (bytes), total ~34.6 MB
    float*          bqkv   = (float*)(ws + 0);            // 768 f
    float*          coefA  = (float*)(ws + 4096);         // 16*256 f
    float*          coefB  = (float*)(ws + 20480);        // 16*256 f
    unsigned short* wqkv_t = (unsigned short*)(ws + 36864);    // 393216 B
    unsigned short* wp_t   = (unsigned short*)(ws + 430080);   // 131072 B
    unsigned short* h_t    = (unsigned short*)(ws + 1048576);  // 8.39 MB
    unsigned short* qb     = (unsigned short*)(ws + 9437184);
    unsigned short* kb     = (unsigned short*)(ws + 17825792);
    unsigned short* vb     = (unsigned short*)(ws + 26214400);

    prep_kernel<<<1024, 256, 0, stream>>>(Wq, Wk, Wv, Wp, bq, bk, bv, wqkv_t, wp_t, bqkv);
    gn_stats_kernel<<<512, 256, 0, stream>>>(x, gn_scale, gn_bias, coefA, coefB);
    qkv_kernel<<<dim3(128, 6), 256, 0, stream>>>(x, coefA, coefB, wqkv_t, bqkv, qb, kb, vb);
    attn_kernel<<<dim3(8, 64), 256, 0, stream>>>(qb, kb, vb, h_t);
    proj_kernel<<<dim3(256, 2), 256, 0, stream>>>(h_t, wp_t, bp, x, out);
}